// Round 10
// baseline (309.796 us; speedup 1.0000x reference)
//
#include <hip/hip_runtime.h>
#include <cstdint>
#include <cstddef>

#define NN 50000
#define NE 800000
// DN=128, DE=64, H=8, C=16

#define NODE_BLOCKS 680
#define EDGE_BLOCKS 1368
#define TOTAL_BLOCKS (NODE_BLOCKS + EDGE_BLOCKS)   // 2048
#define NET (NE/64)            // 12500 edge tiles
#define NNT (((NN+63)/64)*4)   // 3128 node tiles

typedef short bf16x8 __attribute__((ext_vector_type(8)));
typedef float f32x4 __attribute__((ext_vector_type(4)));
typedef float f32x2 __attribute__((ext_vector_type(2)));

__device__ __forceinline__ float b2f(unsigned short s) {
  union { unsigned int u; float f; } x; x.u = ((unsigned int)s) << 16; return x.f;
}
__device__ __forceinline__ unsigned short f2b(float f) {
  union { float f; unsigned int u; } x; x.f = f;
  unsigned int r = x.u + 0x7FFFu + ((x.u >> 16) & 1u);
  return (unsigned short)(r >> 16);
}

// ---------------- ws layout (bytes) ----------------
#define WS_WCE    0u          // bf16 [64][128] (16KB)
#define WS_BCE    16384u      // f32 [128]
#define WS_WCEF   20480u      // bf16 frags 8ct*2s*64l*8j (16KB)
#define WS_WALLF  40960u      // bf16 frags 4m*8ct*4s*64l*8j (128KB)
#define WS_BALL   172032u     // f32 [512]
#define WS_QB     180224u     // bf16 [NN][128]
#define WS_KB     12980224u   // fp8 [NN][128] (region oversized)
#define WS_VB     25780224u   // fp8 [NN][128] (region oversized)
#define WS_XR     38580224u   // f32  [NN][128]
#define WS_EB     64180224u   // fp8  [NE][128] (CSR-sorted rows; region oversized)
#define WS_CNT    268980224u  // int [NN]
#define WS_OFF    269180224u  // int [NN]
#define WS_CUR    269380224u  // int [NN]
#define WS_BSUM   269580224u  // int [256]
#define WS_POS    269584320u  // int [NE]
#define WS_SRCS   272784320u  // int [NE]
// end = 275,984,320 B

// W_ce = W_edge @ We (64x128, bf16), b_ce = b_edge @ We (f32)
__global__ void k_prep(const float* __restrict__ W_edge, const float* __restrict__ b_edge,
                       const float* __restrict__ We, unsigned short* __restrict__ wce,
                       float* __restrict__ bce) {
  int i = blockIdx.x;       // 0..63
  int j = threadIdx.x;      // 0..127
  float s = 0.f;
  for (int m = 0; m < 64; ++m) s += W_edge[i*64+m] * We[m*128+j];
  wce[i*128+j] = f2b(s);
  if (i == 0) {
    float bb = 0.f;
    for (int m = 0; m < 64; ++m) bb += b_edge[m] * We[m*128+j];
    bce[j] = bb;
  }
}

// pack wce [64][128] into A-frag layout
__global__ void k_pack_wce(const unsigned short* __restrict__ wce, unsigned short* __restrict__ wcef) {
  int fb = blockIdx.x;           // 0..15
  int ct = fb >> 1, s = fb & 1;
  int l = threadIdx.x;           // 0..63
  unsigned short* dst = wcef + (((size_t)(ct*2+s))*64 + l)*8;
  int col = ct*16 + (l & 15);
  int k0 = s*32 + (l >> 4)*8;
  #pragma unroll
  for (int j = 0; j < 8; ++j) dst[j] = wce[(k0+j)*128 + col];
}

// pack Wq/Wk/Wv/Wskip (fp32 [128][128], y=x@W layout) into bf16 A-frags
__global__ void k_pack_wall(const float* __restrict__ Wq, const float* __restrict__ Wk,
                            const float* __restrict__ Wv, const float* __restrict__ Ws,
                            unsigned short* __restrict__ wallf) {
  int fb = blockIdx.x;           // 0..127
  int mat = fb >> 5, ct = (fb >> 2) & 7, s = fb & 3;
  int l = threadIdx.x;
  const float* W = (mat==0) ? Wq : (mat==1) ? Wk : (mat==2) ? Wv : Ws;
  unsigned short* dst = wallf + ((((size_t)(mat*8+ct))*4 + s)*64 + l)*8;
  int col = ct*16 + (l & 15);
  int k0 = s*32 + (l >> 4)*8;
  #pragma unroll
  for (int j = 0; j < 8; ++j) dst[j] = f2b(W[(k0+j)*128 + col]);
}

__global__ void k_pack_bias(const float* __restrict__ bq, const float* __restrict__ bk,
                            const float* __restrict__ bv, const float* __restrict__ bs,
                            float* __restrict__ ball) {
  int m = blockIdx.x, c = threadIdx.x;
  const float* b = (m==0) ? bq : (m==1) ? bk : (m==2) ? bv : bs;
  ball[m*128 + c] = b[c];
}

// ---------- persistent fused MFMA kernel ----------
// blocks [0,NODE_BLOCKS): node-linear tiles (64 nodes x 128 cols of one matrix)
// blocks [NODE_BLOCKS,TOTAL): edge-GEMM tiles (64 edges), register-prefetch
// double-buffered across grid-stride iterations; eb fp8 rows CSR-scattered.
__global__ void __launch_bounds__(256) k_mfma_all(
    const float* __restrict__ x, const unsigned short* __restrict__ wallf,
    const float* __restrict__ ball,
    unsigned short* __restrict__ qb, unsigned char* __restrict__ kb,
    unsigned char* __restrict__ vb, float* __restrict__ xr,
    const float* __restrict__ es, const unsigned short* __restrict__ wcef,
    const float* __restrict__ bce, const int* __restrict__ pos,
    unsigned char* __restrict__ eb) {
  __shared__ unsigned short sA[64*128];   // 16KB (node: all; edge: first 8KB)
  __shared__ unsigned char  sO8[64*160];  // 10KB fp8 output staging
  int l = threadIdx.x & 63, w = threadIdx.x >> 6;
  int g = l >> 4, ln = l & 15;

  if (blockIdx.x < NODE_BLOCKS) {
    // ---------------- node blocks ----------------
    for (int tile = blockIdx.x; tile < NNT; tile += NODE_BLOCKS) {
      int mat = tile & 3;
      int n0 = (tile >> 2) * 64;
      for (int i = 0; i < 4; ++i) {
        int c = threadIdx.x + i*256;       // 0..1023
        int row = c >> 4, ch = c & 15;
        int sw = (ch & 8) | ((ch & 7) ^ (row & 7));
        unsigned short tmp[8];
        if (n0 + row < NN) {
          const float* src = x + (size_t)(n0+row)*128 + ch*8;
          float4 f0 = *(const float4*)src;
          float4 f1 = *(const float4*)(src + 4);
          tmp[0]=f2b(f0.x); tmp[1]=f2b(f0.y); tmp[2]=f2b(f0.z); tmp[3]=f2b(f0.w);
          tmp[4]=f2b(f1.x); tmp[5]=f2b(f1.y); tmp[6]=f2b(f1.z); tmp[7]=f2b(f1.w);
        } else {
          #pragma unroll
          for (int j = 0; j < 8; ++j) tmp[j] = 0;
        }
        *(uint4*)&sA[row*128 + sw*8] = *(const uint4*)tmp;
      }
      __syncthreads();
      f32x4 acc[8];
      #pragma unroll
      for (int ct = 0; ct < 8; ++ct) acc[ct] = (f32x4){0.f,0.f,0.f,0.f};
      int row = w*16 + ln;
      for (int s = 0; s < 4; ++s) {
        int ch = s*4 + g;
        int sw = (ch & 8) | ((ch & 7) ^ (row & 7));
        bf16x8 bfr = *(const bf16x8*)&sA[row*128 + sw*8];
        #pragma unroll
        for (int ct = 0; ct < 8; ++ct) {
          bf16x8 wf = *(const bf16x8*)(wallf + ((((size_t)(mat*8+ct))*4 + s)*64 + l)*8);
          acc[ct] = __builtin_amdgcn_mfma_f32_16x16x32_bf16(wf, bfr, acc[ct], 0, 0, 0);
        }
      }
      int node = n0 + row;
      if (node < NN) {
        #pragma unroll
        for (int ct = 0; ct < 8; ++ct) {
          int c0 = ct*16 + g*4;
          float4 bi = *(const float4*)(ball + mat*128 + c0);
          float v0 = acc[ct][0] + bi.x, v1 = acc[ct][1] + bi.y;
          float v2 = acc[ct][2] + bi.z, v3 = acc[ct][3] + bi.w;
          if (mat == 3) {
            float4 o = {v0, v1, v2, v3};
            *(float4*)(xr + (size_t)node*128 + c0) = o;
          } else if (mat == 0) {
            unsigned short o[4] = {f2b(v0), f2b(v1), f2b(v2), f2b(v3)};
            *(uint2*)(qb + (size_t)node*128 + c0) = *(const uint2*)o;
          } else {
            int pk = 0;
            pk = __builtin_amdgcn_cvt_pk_fp8_f32(v0, v1, pk, false);
            pk = __builtin_amdgcn_cvt_pk_fp8_f32(v2, v3, pk, true);
            unsigned char* dst = (mat==1) ? kb : vb;
            *(int*)(dst + (size_t)node*128 + c0) = pk;
          }
        }
      }
      __syncthreads();   // protect sA reuse next iteration
    }
  } else {
    // ---------------- edge blocks (pipelined) ----------------
    int row = threadIdx.x >> 3, ch = threadIdx.x & 7;   // staging coords
    float4 A0, A1, A2, A3; int Ap0 = 0, Ap1 = 0;
    float4 B0, B1, B2, B3; int Bp0 = 0, Bp1 = 0;

#define PFLOAD(T, a0, a1, a2, a3, p0, p1) do {                          \
    int e0_ = (T)*64;                                                   \
    const float* s0_ = es + (size_t)(e0_ + row)*64 + ch*8;              \
    a0 = *(const float4*)s0_; a1 = *(const float4*)(s0_ + 4);           \
    const float* s1_ = s0_ + 32*64;                                     \
    a2 = *(const float4*)s1_; a3 = *(const float4*)(s1_ + 4);           \
    p0 = pos[e0_ + row]; p1 = pos[e0_ + 32 + row];                      \
  } while (0)

#define ESTAGE(a0, a1, a2, a3) do {                                     \
    unsigned short t_[8];                                               \
    t_[0]=f2b(a0.x); t_[1]=f2b(a0.y); t_[2]=f2b(a0.z); t_[3]=f2b(a0.w); \
    t_[4]=f2b(a1.x); t_[5]=f2b(a1.y); t_[6]=f2b(a1.z); t_[7]=f2b(a1.w); \
    *(uint4*)&sA[row*64 + (ch^(row&7))*8] = *(const uint4*)t_;          \
    t_[0]=f2b(a2.x); t_[1]=f2b(a2.y); t_[2]=f2b(a2.z); t_[3]=f2b(a2.w); \
    t_[4]=f2b(a3.x); t_[5]=f2b(a3.y); t_[6]=f2b(a3.z); t_[7]=f2b(a3.w); \
    int r2_ = row + 32;                                                 \
    *(uint4*)&sA[r2_*64 + (ch^(r2_&7))*8] = *(const uint4*)t_;          \
  } while (0)

#define ECOMPUTE(p0, p1) do {                                           \
    __syncthreads();                                                    \
    f32x4 acc[8];                                                       \
    _Pragma("unroll")                                                   \
    for (int ct = 0; ct < 8; ++ct) acc[ct] = (f32x4){0.f,0.f,0.f,0.f};  \
    int mrow_ = w*16 + ln;                                              \
    _Pragma("unroll")                                                   \
    for (int s = 0; s < 2; ++s) {                                       \
      int ch_ = (s*4 + g) ^ (mrow_ & 7);                                \
      bf16x8 bfr_ = *(const bf16x8*)&sA[mrow_*64 + ch_*8];              \
      _Pragma("unroll")                                                 \
      for (int ct = 0; ct < 8; ++ct) {                                  \
        bf16x8 wf_ = *(const bf16x8*)(wcef + (((size_t)(ct*2+s))*64 + l)*8); \
        acc[ct] = __builtin_amdgcn_mfma_f32_16x16x32_bf16(wf_, bfr_, acc[ct], 0, 0, 0); \
      }                                                                 \
    }                                                                   \
    _Pragma("unroll")                                                   \
    for (int ct = 0; ct < 8; ++ct) {                                    \
      int c0_ = ct*16 + g*4;                                            \
      float4 bi_ = *(const float4*)(bce + c0_);                         \
      int pk_ = 0;                                                      \
      pk_ = __builtin_amdgcn_cvt_pk_fp8_f32(acc[ct][0]+bi_.x, acc[ct][1]+bi_.y, pk_, false); \
      pk_ = __builtin_amdgcn_cvt_pk_fp8_f32(acc[ct][2]+bi_.z, acc[ct][3]+bi_.w, pk_, true);  \
      *(int*)&sO8[mrow_*160 + (ct^(mrow_&7))*16 + g*4] = pk_;           \
    }                                                                   \
    __syncthreads();                                                    \
    {                                                                   \
      uint4 v0_ = *(const uint4*)&sO8[row*160 + (ch^(row&7))*16];       \
      *(uint4*)(eb + (size_t)(p0)*128 + ch*16) = v0_;                   \
      int r2_ = row + 32;                                               \
      uint4 v1_ = *(const uint4*)&sO8[r2_*160 + (ch^(r2_&7))*16];       \
      *(uint4*)(eb + (size_t)(p1)*128 + ch*16) = v1_;                   \
    }                                                                   \
  } while (0)

    int t = blockIdx.x - NODE_BLOCKS;     // 0..EDGE_BLOCKS-1
    if (t < NET) {
      PFLOAD(t, A0, A1, A2, A3, Ap0, Ap1);
      while (true) {
        int t2 = t + EDGE_BLOCKS;
        ESTAGE(A0, A1, A2, A3);
        if (t2 < NET) PFLOAD(t2, B0, B1, B2, B3, Bp0, Bp1);
        ECOMPUTE(Ap0, Ap1);
        if (t2 >= NET) break;
        int t3 = t2 + EDGE_BLOCKS;
        ESTAGE(B0, B1, B2, B3);
        if (t3 < NET) PFLOAD(t3, A0, A1, A2, A3, Ap0, Ap1);
        ECOMPUTE(Bp0, Bp1);
        if (t3 >= NET) break;
        t = t3;
      }
    }
#undef PFLOAD
#undef ESTAGE
#undef ECOMPUTE
  }
}

// -------- CSR build --------
__global__ void __launch_bounds__(256) k_hist(const int* __restrict__ ei, int* __restrict__ cnt) {
  int t = blockIdx.x * 256 + threadIdx.x;
  if (t < NE) atomicAdd(&cnt[ei[NE + t]], 1);
}

__global__ void __launch_bounds__(256) k_scanA(const int* __restrict__ cnt,
    int* __restrict__ off, int* __restrict__ bsum) {
  __shared__ int s[256];
  int i = blockIdx.x * 256 + threadIdx.x;
  int v = (i < NN) ? cnt[i] : 0;
  s[threadIdx.x] = v;
  __syncthreads();
  #pragma unroll
  for (int d = 1; d < 256; d <<= 1) {
    int t = (threadIdx.x >= d) ? s[threadIdx.x - d] : 0;
    __syncthreads();
    s[threadIdx.x] += t;
    __syncthreads();
  }
  if (i < NN) off[i] = s[threadIdx.x] - v;
  if (threadIdx.x == 255) bsum[blockIdx.x] = s[255];
}

__global__ void __launch_bounds__(256) k_scanB(int* __restrict__ bsum, int nb) {
  __shared__ int s[256];
  int v = (threadIdx.x < nb) ? bsum[threadIdx.x] : 0;
  s[threadIdx.x] = v;
  __syncthreads();
  #pragma unroll
  for (int d = 1; d < 256; d <<= 1) {
    int t = (threadIdx.x >= d) ? s[threadIdx.x - d] : 0;
    __syncthreads();
    s[threadIdx.x] += t;
    __syncthreads();
  }
  if (threadIdx.x < nb) bsum[threadIdx.x] = s[threadIdx.x] - v;
}

__global__ void __launch_bounds__(256) k_scanC(int* __restrict__ off,
    const int* __restrict__ bsum, int* __restrict__ cur) {
  int i = blockIdx.x * 256 + threadIdx.x;
  if (i < NN) {
    int o = off[i] + bsum[blockIdx.x];
    off[i] = o;
    cur[i] = o;
  }
}

// records each edge's CSR slot (pos) and the slot's source node (srcs)
__global__ void __launch_bounds__(256) k_scatter(const int* __restrict__ ei,
    int* __restrict__ cur, int* __restrict__ pos, int* __restrict__ srcs) {
  int t = blockIdx.x * 256 + threadIdx.x;
  if (t < NE) {
    int d = ei[NE + t];
    int p = atomicAdd(&cur[d], 1);
    pos[t] = p;
    srcs[p] = ei[t];
  }
}

// -------- fused attention gather + beta-gate + LN + residual ReLU --------
// one wave per node; lane l owns channels 2l, 2l+1; head = l>>3
__global__ void __launch_bounds__(256) k_attn(
    const int* __restrict__ off, const int* __restrict__ cnt,
    const int* __restrict__ srcs,
    const unsigned short* __restrict__ qb, const unsigned char* __restrict__ kb,
    const unsigned char* __restrict__ vb, const unsigned char* __restrict__ eb,
    const float* __restrict__ xr, const float* __restrict__ x,
    const float* __restrict__ Wb, const float* __restrict__ ln_g,
    const float* __restrict__ ln_b, float* __restrict__ out) {
  int wid = threadIdx.x >> 6, lane = threadIdx.x & 63;
  int n = blockIdx.x * 4 + wid;
  if (n >= NN) return;
  int c = lane * 2;

  unsigned int qu = *(const unsigned int*)(qb + (size_t)n*128 + c);
  float q0 = b2f((unsigned short)(qu & 0xffffu)), q1 = b2f((unsigned short)(qu >> 16));

  int start = off[n], m = cnt[n];
  const int* sp = srcs + start;
  const unsigned char* ep = eb + (size_t)start*128 + c;
  float acc0 = 0.f, acc1 = 0.f, den = 0.f;

  auto body = [&](unsigned int ku2, unsigned int eu2, unsigned int vu2) {
    f32x2 ef = __builtin_amdgcn_cvt_pk_f32_fp8((int)eu2, false);
    f32x2 kf = __builtin_amdgcn_cvt_pk_f32_fp8((int)ku2, false);
    f32x2 vf = __builtin_amdgcn_cvt_pk_f32_fp8((int)vu2, false);
    float p = q0*(kf[0] + ef[0]) + q1*(kf[1] + ef[1]);
    p += __shfl_xor(p, 1);
    p += __shfl_xor(p, 2);
    p += __shfl_xor(p, 4);
    float a = __expf(p * 0.25f);
    den  += a;
    acc0 += a * (vf[0] + ef[0]);
    acc1 += a * (vf[1] + ef[1]);
  };

  int i = 0;
  for (; i + 8 <= m; i += 8) {
    int sn[8]; unsigned int eu[8], ku[8], vu[8];
    #pragma unroll
    for (int j = 0; j < 8; ++j) sn[j] = sp[i+j];
    #pragma unroll
    for (int j = 0; j < 8; ++j) eu[j] = *(const unsigned short*)(ep + (size_t)(i+j)*128);
    #pragma unroll
    for (int j = 0; j < 8; ++j) {
      ku[j] = *(const unsigned short*)(kb + (size_t)sn[j]*128 + c);
      vu[j] = *(const unsigned short*)(vb + (size_t)sn[j]*128 + c);
    }
    #pragma unroll
    for (int j = 0; j < 8; ++j) body(ku[j], eu[j], vu[j]);
  }
  for (; i + 4 <= m; i += 4) {
    int sn[4]; unsigned int eu[4], ku[4], vu[4];
    #pragma unroll
    for (int j = 0; j < 4; ++j) sn[j] = sp[i+j];
    #pragma unroll
    for (int j = 0; j < 4; ++j) eu[j] = *(const unsigned short*)(ep + (size_t)(i+j)*128);
    #pragma unroll
    for (int j = 0; j < 4; ++j) {
      ku[j] = *(const unsigned short*)(kb + (size_t)sn[j]*128 + c);
      vu[j] = *(const unsigned short*)(vb + (size_t)sn[j]*128 + c);
    }
    #pragma unroll
    for (int j = 0; j < 4; ++j) body(ku[j], eu[j], vu[j]);
  }
  for (; i < m; ++i) {
    int sA = sp[i];
    unsigned int euA = *(const unsigned short*)(ep + (size_t)i*128);
    unsigned int kuA = *(const unsigned short*)(kb + (size_t)sA*128 + c);
    unsigned int vuA = *(const unsigned short*)(vb + (size_t)sA*128 + c);
    body(kuA, euA, vuA);
  }

  float inv = (m > 0) ? 1.f / den : 0.f;
  float o0 = acc0 * inv, o1 = acc1 * inv;

  // epilogue
  float2 r = *(const float2*)(xr + (size_t)n*128 + c);
  float p = o0*Wb[c] + o1*Wb[c+1] + r.x*Wb[128+c] + r.y*Wb[128+c+1]
          + (o0-r.x)*Wb[256+c] + (o1-r.y)*Wb[256+c+1];
  #pragma unroll
  for (int offs = 32; offs > 0; offs >>= 1) p += __shfl_xor(p, offs);
  float beta = 1.f / (1.f + __expf(-p));
  float g0 = beta*r.x + (1.f-beta)*o0;
  float g1 = beta*r.y + (1.f-beta)*o1;
  float msum = g0 + g1;
  #pragma unroll
  for (int offs = 32; offs > 0; offs >>= 1) msum += __shfl_xor(msum, offs);
  msum *= (1.f/128.f);
  float d0 = g0 - msum, d1 = g1 - msum;
  float vv = d0*d0 + d1*d1;
  #pragma unroll
  for (int offs = 32; offs > 0; offs >>= 1) vv += __shfl_xor(vv, offs);
  vv *= (1.f/128.f);
  float rs = rsqrtf(vv + 1e-5f);
  float n0 = d0*rs*ln_g[c]   + ln_b[c];
  float n1 = d1*rs*ln_g[c+1] + ln_b[c+1];
  float2 xv = *(const float2*)(x + (size_t)n*128 + c);
  float2 res;
  res.x = xv.x + fmaxf(n0, 0.f);
  res.y = xv.y + fmaxf(n1, 0.f);
  *(float2*)(out + (size_t)n*128 + c) = res;
}

extern "C" void kernel_launch(void* const* d_in, const int* in_sizes, int n_in,
                              void* d_out, int out_size, void* d_ws, size_t ws_size,
                              hipStream_t stream) {
  const float* node   = (const float*)d_in[0];
  const int*   ei     = (const int*)  d_in[1];
  const float* es     = (const float*)d_in[2];
  const float* W_edge = (const float*)d_in[3];
  const float* b_edge = (const float*)d_in[4];
  const float* Wq     = (const float*)d_in[5];
  const float* bq     = (const float*)d_in[6];
  const float* Wk     = (const float*)d_in[7];
  const float* bk     = (const float*)d_in[8];
  const float* Wv     = (const float*)d_in[9];
  const float* bv     = (const float*)d_in[10];
  const float* We     = (const float*)d_in[11];
  const float* Wskip  = (const float*)d_in[12];
  const float* bskip  = (const float*)d_in[13];
  const float* Wbeta  = (const float*)d_in[14];
  const float* ln_g   = (const float*)d_in[15];
  const float* ln_b   = (const float*)d_in[16];

  char* ws = (char*)d_ws;
  unsigned short* wce   = (unsigned short*)(ws + WS_WCE);
  float*          bce   = (float*)(ws + WS_BCE);
  unsigned short* wcef  = (unsigned short*)(ws + WS_WCEF);
  unsigned short* wallf = (unsigned short*)(ws + WS_WALLF);
  float*          ball  = (float*)(ws + WS_BALL);
  unsigned short* qb  = (unsigned short*)(ws + WS_QB);
  unsigned char*  kb  = (unsigned char*)(ws + WS_KB);
  unsigned char*  vb  = (unsigned char*)(ws + WS_VB);
  float*          xr  = (float*)(ws + WS_XR);
  unsigned char*  eb  = (unsigned char*)(ws + WS_EB);
  int*            cnt = (int*)(ws + WS_CNT);
  int*            off = (int*)(ws + WS_OFF);
  int*            cur = (int*)(ws + WS_CUR);
  int*            bsm = (int*)(ws + WS_BSUM);
  int*            pos = (int*)(ws + WS_POS);
  int*            srcs= (int*)(ws + WS_SRCS);

  hipMemsetAsync(cnt, 0, (size_t)NN*4, stream);

  k_prep<<<64, 128, 0, stream>>>(W_edge, b_edge, We, wce, bce);
  k_pack_wce<<<16, 64, 0, stream>>>(wce, wcef);
  k_pack_wall<<<128, 64, 0, stream>>>(Wq, Wk, Wv, Wskip, wallf);
  k_pack_bias<<<4, 128, 0, stream>>>(bq, bk, bv, bskip, ball);

  const int nbScan = (NN + 255)/256;  // 196
  k_hist<<<(NE + 255)/256, 256, 0, stream>>>(ei, cnt);
  k_scanA<<<nbScan, 256, 0, stream>>>(cnt, off, bsm);
  k_scanB<<<1, 256, 0, stream>>>(bsm, nbScan);
  k_scanC<<<nbScan, 256, 0, stream>>>(off, bsm, cur);
  k_scatter<<<(NE + 255)/256, 256, 0, stream>>>(ei, cur, pos, srcs);

  k_mfma_all<<<TOTAL_BLOCKS, 256, 0, stream>>>(node, wallf, ball, qb, kb, vb, xr,
                                               es, wcef, bce, pos, eb);

  k_attn<<<(NN + 3)/4, 256, 0, stream>>>(off, cnt, srcs, qb, kb, vb, eb,
                                         xr, node, Wbeta, ln_g, ln_b, (float*)d_out);
}

// Round 11
// 291.734 us; speedup vs baseline: 1.0619x; 1.0619x over previous
//
#include <hip/hip_runtime.h>
#include <cstdint>
#include <cstddef>

#define NN 50000
#define NE 800000
// DN=128, DE=64, H=8, C=16

#define NNT ((NN + 63)/64)     // 782 node tiles (each does all 4 mats)
#define NET (NE/64)            // 12500 edge tiles

typedef short bf16x8 __attribute__((ext_vector_type(8)));
typedef float f32x4 __attribute__((ext_vector_type(4)));
typedef float f32x2 __attribute__((ext_vector_type(2)));

__device__ __forceinline__ float b2f(unsigned short s) {
  union { unsigned int u; float f; } x; x.u = ((unsigned int)s) << 16; return x.f;
}
__device__ __forceinline__ unsigned short f2b(float f) {
  union { float f; unsigned int u; } x; x.f = f;
  unsigned int r = x.u + 0x7FFFu + ((x.u >> 16) & 1u);
  return (unsigned short)(r >> 16);
}

// ---------------- ws layout (bytes) ----------------
#define WS_WCE    0u          // bf16 [64][128] (16KB)
#define WS_BCE    16384u      // f32 [128]
#define WS_WCEF   20480u      // bf16 frags 8ct*2s*64l*8j (16KB)
#define WS_WALLF  40960u      // bf16 frags 4m*8ct*4s*64l*8j (128KB)
#define WS_BALL   172032u     // f32 [512]
#define WS_QB     180224u     // bf16 [NN][128]
#define WS_KB     12980224u   // fp8 [NN][128] (region oversized)
#define WS_VB     25780224u   // fp8 [NN][128] (region oversized)
#define WS_XR     38580224u   // f32  [NN][128]
#define WS_EB     64180224u   // fp8  [NE][128] (CSR-sorted rows; region oversized)
#define WS_CNT    268980224u  // int [NN]
#define WS_OFF    269180224u  // int [NN]
#define WS_CUR    269380224u  // int [NN]
#define WS_BSUM   269580224u  // int [256]
#define WS_POS    269584320u  // int [NE]
#define WS_SRCS   272784320u  // int [NE]
// end = 275,984,320 B

// W_ce = W_edge @ We (64x128, bf16), b_ce = b_edge @ We (f32)
__global__ void k_prep(const float* __restrict__ W_edge, const float* __restrict__ b_edge,
                       const float* __restrict__ We, unsigned short* __restrict__ wce,
                       float* __restrict__ bce) {
  int i = blockIdx.x;       // 0..63
  int j = threadIdx.x;      // 0..127
  float s = 0.f;
  for (int m = 0; m < 64; ++m) s += W_edge[i*64+m] * We[m*128+j];
  wce[i*128+j] = f2b(s);
  if (i == 0) {
    float bb = 0.f;
    for (int m = 0; m < 64; ++m) bb += b_edge[m] * We[m*128+j];
    bce[j] = bb;
  }
}

// pack wce [64][128] into A-frag layout
__global__ void k_pack_wce(const unsigned short* __restrict__ wce, unsigned short* __restrict__ wcef) {
  int fb = blockIdx.x;           // 0..15
  int ct = fb >> 1, s = fb & 1;
  int l = threadIdx.x;           // 0..63
  unsigned short* dst = wcef + (((size_t)(ct*2+s))*64 + l)*8;
  int col = ct*16 + (l & 15);
  int k0 = s*32 + (l >> 4)*8;
  #pragma unroll
  for (int j = 0; j < 8; ++j) dst[j] = wce[(k0+j)*128 + col];
}

// pack Wq/Wk/Wv/Wskip (fp32 [128][128], y=x@W layout) into bf16 A-frags
__global__ void k_pack_wall(const float* __restrict__ Wq, const float* __restrict__ Wk,
                            const float* __restrict__ Wv, const float* __restrict__ Ws,
                            unsigned short* __restrict__ wallf) {
  int fb = blockIdx.x;           // 0..127
  int mat = fb >> 5, ct = (fb >> 2) & 7, s = fb & 3;
  int l = threadIdx.x;
  const float* W = (mat==0) ? Wq : (mat==1) ? Wk : (mat==2) ? Wv : Ws;
  unsigned short* dst = wallf + ((((size_t)(mat*8+ct))*4 + s)*64 + l)*8;
  int col = ct*16 + (l & 15);
  int k0 = s*32 + (l >> 4)*8;
  #pragma unroll
  for (int j = 0; j < 8; ++j) dst[j] = f2b(W[(k0+j)*128 + col]);
}

__global__ void k_pack_bias(const float* __restrict__ bq, const float* __restrict__ bk,
                            const float* __restrict__ bv, const float* __restrict__ bs,
                            float* __restrict__ ball) {
  int m = blockIdx.x, c = threadIdx.x;
  const float* b = (m==0) ? bq : (m==1) ? bk : (m==2) ? bv : bs;
  ball[m*128 + c] = b[c];
}

// ---------- fused MFMA kernel ----------
// b % 17 == 0 : node tile (64 nodes; x staged ONCE, all 4 matrices computed)
// otherwise   : edge tile (64 edges; fp8 rows CSR-scattered via LDS-prefetched pos)
__global__ void __launch_bounds__(256) k_mfma_all(
    const float* __restrict__ x, const unsigned short* __restrict__ wallf,
    const float* __restrict__ ball,
    unsigned short* __restrict__ qb, unsigned char* __restrict__ kb,
    unsigned char* __restrict__ vb, float* __restrict__ xr,
    const float* __restrict__ es, const unsigned short* __restrict__ wcef,
    const float* __restrict__ bce, const int* __restrict__ pos,
    unsigned char* __restrict__ eb) {
  __shared__ char smem[18688];
  int b = blockIdx.x;
  int l = threadIdx.x & 63, w = threadIdx.x >> 6;
  int g = l >> 4, ln = l & 15;

  if (b % 17 == 0) {
    // ---- node tile: stage once, compute 4 matrices ----
    int tile = b / 17;
    if (tile >= NNT) return;
    int n0 = tile * 64;
    unsigned short* sA = (unsigned short*)smem;   // [64][128] bf16, swizzled
    for (int i = 0; i < 4; ++i) {
      int c = threadIdx.x + i*256;       // 0..1023
      int row = c >> 4, ch = c & 15;
      int sw = (ch & 8) | ((ch & 7) ^ (row & 7));
      unsigned short tmp[8];
      if (n0 + row < NN) {
        const float* src = x + (size_t)(n0+row)*128 + ch*8;
        float4 f0 = *(const float4*)src;
        float4 f1 = *(const float4*)(src + 4);
        tmp[0]=f2b(f0.x); tmp[1]=f2b(f0.y); tmp[2]=f2b(f0.z); tmp[3]=f2b(f0.w);
        tmp[4]=f2b(f1.x); tmp[5]=f2b(f1.y); tmp[6]=f2b(f1.z); tmp[7]=f2b(f1.w);
      } else {
        #pragma unroll
        for (int j = 0; j < 8; ++j) tmp[j] = 0;
      }
      *(uint4*)&sA[row*128 + sw*8] = *(const uint4*)tmp;
    }
    __syncthreads();
    int row = w*16 + ln;
    int node = n0 + row;
    // preload B-fragments (shared across mats)
    bf16x8 bfr[4];
    #pragma unroll
    for (int s = 0; s < 4; ++s) {
      int ch = s*4 + g;
      int sw = (ch & 8) | ((ch & 7) ^ (row & 7));
      bfr[s] = *(const bf16x8*)&sA[row*128 + sw*8];
    }
    for (int mat = 0; mat < 4; ++mat) {
      f32x4 acc[8];
      #pragma unroll
      for (int ct = 0; ct < 8; ++ct) acc[ct] = (f32x4){0.f,0.f,0.f,0.f};
      #pragma unroll
      for (int s = 0; s < 4; ++s) {
        #pragma unroll
        for (int ct = 0; ct < 8; ++ct) {
          bf16x8 wf = *(const bf16x8*)(wallf + ((((size_t)(mat*8+ct))*4 + s)*64 + l)*8);
          acc[ct] = __builtin_amdgcn_mfma_f32_16x16x32_bf16(wf, bfr[s], acc[ct], 0, 0, 0);
        }
      }
      if (node < NN) {
        #pragma unroll
        for (int ct = 0; ct < 8; ++ct) {
          int c0 = ct*16 + g*4;
          float4 bi = *(const float4*)(ball + mat*128 + c0);
          float v0 = acc[ct][0] + bi.x, v1 = acc[ct][1] + bi.y;
          float v2 = acc[ct][2] + bi.z, v3 = acc[ct][3] + bi.w;
          if (mat == 3) {
            float4 o = {v0, v1, v2, v3};
            *(float4*)(xr + (size_t)node*128 + c0) = o;
          } else if (mat == 0) {
            unsigned short o[4] = {f2b(v0), f2b(v1), f2b(v2), f2b(v3)};
            *(uint2*)(qb + (size_t)node*128 + c0) = *(const uint2*)o;
          } else {
            int pk = 0;
            pk = __builtin_amdgcn_cvt_pk_fp8_f32(v0, v1, pk, false);
            pk = __builtin_amdgcn_cvt_pk_fp8_f32(v2, v3, pk, true);
            unsigned char* dst = (mat==1) ? kb : vb;
            *(int*)(dst + (size_t)node*128 + c0) = pk;
          }
        }
      }
    }
  } else {
    // ---- edge tile ----
    int tile = b - b/17 - 1;
    if (tile >= NET) return;
    int e0 = tile * 64;
    unsigned short* sA  = (unsigned short*)smem;            // [64][64] bf16 (8KB)
    unsigned char*  sO8 = (unsigned char*)(smem + 8192);    // [64][160] fp8 (10KB)
    int*            sP  = (int*)(smem + 18432);             // [64] pos
    if (threadIdx.x < 64) sP[threadIdx.x] = pos[e0 + threadIdx.x];
    for (int i = 0; i < 2; ++i) {
      int c = threadIdx.x + i*256;       // 0..511
      int row = c >> 3, ch = c & 7;
      int sw = ch ^ (row & 7);
      const float* src = es + (size_t)(e0+row)*64 + ch*8;
      float4 f0 = *(const float4*)src;
      float4 f1 = *(const float4*)(src + 4);
      unsigned short tmp[8];
      tmp[0]=f2b(f0.x); tmp[1]=f2b(f0.y); tmp[2]=f2b(f0.z); tmp[3]=f2b(f0.w);
      tmp[4]=f2b(f1.x); tmp[5]=f2b(f1.y); tmp[6]=f2b(f1.z); tmp[7]=f2b(f1.w);
      *(uint4*)&sA[row*64 + sw*8] = *(const uint4*)tmp;
    }
    __syncthreads();
    f32x4 acc[8];
    #pragma unroll
    for (int ct = 0; ct < 8; ++ct) acc[ct] = (f32x4){0.f,0.f,0.f,0.f};
    int row = w*16 + ln;
    #pragma unroll
    for (int s = 0; s < 2; ++s) {
      int ch = (s*4 + g) ^ (row & 7);
      bf16x8 bfr = *(const bf16x8*)&sA[row*64 + ch*8];
      #pragma unroll
      for (int ct = 0; ct < 8; ++ct) {
        bf16x8 wf = *(const bf16x8*)(wcef + (((size_t)(ct*2+s))*64 + l)*8);
        acc[ct] = __builtin_amdgcn_mfma_f32_16x16x32_bf16(wf, bfr, acc[ct], 0, 0, 0);
      }
    }
    // stage fp8 (+bias) into swizzled LDS
    #pragma unroll
    for (int ct = 0; ct < 8; ++ct) {
      int c0 = ct*16 + g*4;
      float4 bi = *(const float4*)(bce + c0);
      int pk = 0;
      pk = __builtin_amdgcn_cvt_pk_fp8_f32(acc[ct][0]+bi.x, acc[ct][1]+bi.y, pk, false);
      pk = __builtin_amdgcn_cvt_pk_fp8_f32(acc[ct][2]+bi.z, acc[ct][3]+bi.w, pk, true);
      int ch = ct ^ (row & 7);
      *(int*)&sO8[row*160 + ch*16 + g*4] = pk;
    }
    __syncthreads();
    // readback: 8 lanes x 16B = one full 128B fp8 row per 8-lane group
    int rrow = threadIdx.x >> 3;   // 0..31
    int rch  = threadIdx.x & 7;
    #pragma unroll
    for (int it = 0; it < 2; ++it) {
      int r = it*32 + rrow;
      int swc = rch ^ (r & 7);
      uint4 val = *(const uint4*)&sO8[r*160 + swc*16];
      int prow = sP[r];
      *(uint4*)(eb + (size_t)prow*128 + rch*16) = val;
    }
  }
}

// -------- CSR build --------
__global__ void __launch_bounds__(256) k_hist(const int* __restrict__ ei, int* __restrict__ cnt) {
  int t = blockIdx.x * 256 + threadIdx.x;
  if (t < NE) atomicAdd(&cnt[ei[NE + t]], 1);
}

__global__ void __launch_bounds__(256) k_scanA(const int* __restrict__ cnt,
    int* __restrict__ off, int* __restrict__ bsum) {
  __shared__ int s[256];
  int i = blockIdx.x * 256 + threadIdx.x;
  int v = (i < NN) ? cnt[i] : 0;
  s[threadIdx.x] = v;
  __syncthreads();
  #pragma unroll
  for (int d = 1; d < 256; d <<= 1) {
    int t = (threadIdx.x >= d) ? s[threadIdx.x - d] : 0;
    __syncthreads();
    s[threadIdx.x] += t;
    __syncthreads();
  }
  if (i < NN) off[i] = s[threadIdx.x] - v;
  if (threadIdx.x == 255) bsum[blockIdx.x] = s[255];
}

__global__ void __launch_bounds__(256) k_scanB(int* __restrict__ bsum, int nb) {
  __shared__ int s[256];
  int v = (threadIdx.x < nb) ? bsum[threadIdx.x] : 0;
  s[threadIdx.x] = v;
  __syncthreads();
  #pragma unroll
  for (int d = 1; d < 256; d <<= 1) {
    int t = (threadIdx.x >= d) ? s[threadIdx.x - d] : 0;
    __syncthreads();
    s[threadIdx.x] += t;
    __syncthreads();
  }
  if (threadIdx.x < nb) bsum[threadIdx.x] = s[threadIdx.x] - v;
}

__global__ void __launch_bounds__(256) k_scanC(int* __restrict__ off,
    const int* __restrict__ bsum, int* __restrict__ cur) {
  int i = blockIdx.x * 256 + threadIdx.x;
  if (i < NN) {
    int o = off[i] + bsum[blockIdx.x];
    off[i] = o;
    cur[i] = o;
  }
}

// records each edge's CSR slot (pos) and the slot's source node (srcs)
__global__ void __launch_bounds__(256) k_scatter(const int* __restrict__ ei,
    int* __restrict__ cur, int* __restrict__ pos, int* __restrict__ srcs) {
  int t = blockIdx.x * 256 + threadIdx.x;
  if (t < NE) {
    int d = ei[NE + t];
    int p = atomicAdd(&cur[d], 1);
    pos[t] = p;
    srcs[p] = ei[t];
  }
}

// -------- fused attention gather + beta-gate + LN + residual ReLU --------
// one wave per node; lane l owns channels 2l, 2l+1; head = l>>3
__global__ void __launch_bounds__(256) k_attn(
    const int* __restrict__ off, const int* __restrict__ cnt,
    const int* __restrict__ srcs,
    const unsigned short* __restrict__ qb, const unsigned char* __restrict__ kb,
    const unsigned char* __restrict__ vb, const unsigned char* __restrict__ eb,
    const float* __restrict__ xr, const float* __restrict__ x,
    const float* __restrict__ Wb, const float* __restrict__ ln_g,
    const float* __restrict__ ln_b, float* __restrict__ out) {
  int wid = threadIdx.x >> 6, lane = threadIdx.x & 63;
  int n = blockIdx.x * 4 + wid;
  if (n >= NN) return;
  int c = lane * 2;

  unsigned int qu = *(const unsigned int*)(qb + (size_t)n*128 + c);
  float q0 = b2f((unsigned short)(qu & 0xffffu)), q1 = b2f((unsigned short)(qu >> 16));

  int start = off[n], m = cnt[n];
  const int* sp = srcs + start;
  const unsigned char* ep = eb + (size_t)start*128 + c;
  float acc0 = 0.f, acc1 = 0.f, den = 0.f;

  auto body = [&](unsigned int ku2, unsigned int eu2, unsigned int vu2) {
    f32x2 ef = __builtin_amdgcn_cvt_pk_f32_fp8((int)eu2, false);
    f32x2 kf = __builtin_amdgcn_cvt_pk_f32_fp8((int)ku2, false);
    f32x2 vf = __builtin_amdgcn_cvt_pk_f32_fp8((int)vu2, false);
    float p = q0*(kf[0] + ef[0]) + q1*(kf[1] + ef[1]);
    p += __shfl_xor(p, 1);
    p += __shfl_xor(p, 2);
    p += __shfl_xor(p, 4);
    float a = __expf(p * 0.25f);
    den  += a;
    acc0 += a * (vf[0] + ef[0]);
    acc1 += a * (vf[1] + ef[1]);
  };

  int i = 0;
  for (; i + 8 <= m; i += 8) {
    int sn[8]; unsigned int eu[8], ku[8], vu[8];
    #pragma unroll
    for (int j = 0; j < 8; ++j) sn[j] = sp[i+j];
    #pragma unroll
    for (int j = 0; j < 8; ++j) eu[j] = *(const unsigned short*)(ep + (size_t)(i+j)*128);
    #pragma unroll
    for (int j = 0; j < 8; ++j) {
      ku[j] = *(const unsigned short*)(kb + (size_t)sn[j]*128 + c);
      vu[j] = *(const unsigned short*)(vb + (size_t)sn[j]*128 + c);
    }
    #pragma unroll
    for (int j = 0; j < 8; ++j) body(ku[j], eu[j], vu[j]);
  }
  for (; i + 4 <= m; i += 4) {
    int sn[4]; unsigned int eu[4], ku[4], vu[4];
    #pragma unroll
    for (int j = 0; j < 4; ++j) sn[j] = sp[i+j];
    #pragma unroll
    for (int j = 0; j < 4; ++j) eu[j] = *(const unsigned short*)(ep + (size_t)(i+j)*128);
    #pragma unroll
    for (int j = 0; j < 4; ++j) {
      ku[j] = *(const unsigned short*)(kb + (size_t)sn[j]*128 + c);
      vu[j] = *(const unsigned short*)(vb + (size_t)sn[j]*128 + c);
    }
    #pragma unroll
    for (int j = 0; j < 4; ++j) body(ku[j], eu[j], vu[j]);
  }
  for (; i < m; ++i) {
    int sA = sp[i];
    unsigned int euA = *(const unsigned short*)(ep + (size_t)i*128);
    unsigned int kuA = *(const unsigned short*)(kb + (size_t)sA*128 + c);
    unsigned int vuA = *(const unsigned short*)(vb + (size_t)sA*128 + c);
    body(kuA, euA, vuA);
  }

  float inv = (m > 0) ? 1.f / den : 0.f;
  float o0 = acc0 * inv, o1 = acc1 * inv;

  // epilogue
  float2 r = *(const float2*)(xr + (size_t)n*128 + c);
  float p = o0*Wb[c] + o1*Wb[c+1] + r.x*Wb[128+c] + r.y*Wb[128+c+1]
          + (o0-r.x)*Wb[256+c] + (o1-r.y)*Wb[256+c+1];
  #pragma unroll
  for (int offs = 32; offs > 0; offs >>= 1) p += __shfl_xor(p, offs);
  float beta = 1.f / (1.f + __expf(-p));
  float g0 = beta*r.x + (1.f-beta)*o0;
  float g1 = beta*r.y + (1.f-beta)*o1;
  float msum = g0 + g1;
  #pragma unroll
  for (int offs = 32; offs > 0; offs >>= 1) msum += __shfl_xor(msum, offs);
  msum *= (1.f/128.f);
  float d0 = g0 - msum, d1 = g1 - msum;
  float vv = d0*d0 + d1*d1;
  #pragma unroll
  for (int offs = 32; offs > 0; offs >>= 1) vv += __shfl_xor(vv, offs);
  vv *= (1.f/128.f);
  float rs = rsqrtf(vv + 1e-5f);
  float n0 = d0*rs*ln_g[c]   + ln_b[c];
  float n1 = d1*rs*ln_g[c+1] + ln_b[c+1];
  float2 xv = *(const float2*)(x + (size_t)n*128 + c);
  float2 res;
  res.x = xv.x + fmaxf(n0, 0.f);
  res.y = xv.y + fmaxf(n1, 0.f);
  *(float2*)(out + (size_t)n*128 + c) = res;
}

extern "C" void kernel_launch(void* const* d_in, const int* in_sizes, int n_in,
                              void* d_out, int out_size, void* d_ws, size_t ws_size,
                              hipStream_t stream) {
  const float* node   = (const float*)d_in[0];
  const int*   ei     = (const int*)  d_in[1];
  const float* es     = (const float*)d_in[2];
  const float* W_edge = (const float*)d_in[3];
  const float* b_edge = (const float*)d_in[4];
  const float* Wq     = (const float*)d_in[5];
  const float* bq     = (const float*)d_in[6];
  const float* Wk     = (const float*)d_in[7];
  const float* bk     = (const float*)d_in[8];
  const float* Wv     = (const float*)d_in[9];
  const float* bv     = (const float*)d_in[10];
  const float* We     = (const float*)d_in[11];
  const float* Wskip  = (const float*)d_in[12];
  const float* bskip  = (const float*)d_in[13];
  const float* Wbeta  = (const float*)d_in[14];
  const float* ln_g   = (const float*)d_in[15];
  const float* ln_b   = (const float*)d_in[16];

  char* ws = (char*)d_ws;
  unsigned short* wce   = (unsigned short*)(ws + WS_WCE);
  float*          bce   = (float*)(ws + WS_BCE);
  unsigned short* wcef  = (unsigned short*)(ws + WS_WCEF);
  unsigned short* wallf = (unsigned short*)(ws + WS_WALLF);
  float*          ball  = (float*)(ws + WS_BALL);
  unsigned short* qb  = (unsigned short*)(ws + WS_QB);
  unsigned char*  kb  = (unsigned char*)(ws + WS_KB);
  unsigned char*  vb  = (unsigned char*)(ws + WS_VB);
  float*          xr  = (float*)(ws + WS_XR);
  unsigned char*  eb  = (unsigned char*)(ws + WS_EB);
  int*            cnt = (int*)(ws + WS_CNT);
  int*            off = (int*)(ws + WS_OFF);
  int*            cur = (int*)(ws + WS_CUR);
  int*            bsm = (int*)(ws + WS_BSUM);
  int*            pos = (int*)(ws + WS_POS);
  int*            srcs= (int*)(ws + WS_SRCS);

  hipMemsetAsync(cnt, 0, (size_t)NN*4, stream);

  k_prep<<<64, 128, 0, stream>>>(W_edge, b_edge, We, wce, bce);
  k_pack_wce<<<16, 64, 0, stream>>>(wce, wcef);
  k_pack_wall<<<128, 64, 0, stream>>>(Wq, Wk, Wv, Wskip, wallf);
  k_pack_bias<<<4, 128, 0, stream>>>(bq, bk, bv, bskip, ball);

  const int nbScan = (NN + 255)/256;  // 196
  k_hist<<<(NE + 255)/256, 256, 0, stream>>>(ei, cnt);
  k_scanA<<<nbScan, 256, 0, stream>>>(cnt, off, bsm);
  k_scanB<<<1, 256, 0, stream>>>(bsm, nbScan);
  k_scanC<<<nbScan, 256, 0, stream>>>(off, bsm, cur);
  k_scatter<<<(NE + 255)/256, 256, 0, stream>>>(ei, cur, pos, srcs);

  // grid: node tiles at b%17==0 (782 of them), edge tiles elsewhere (12512 slots >= 12500)
  const int grid = 17 * NNT;   // 13294
  k_mfma_all<<<grid, 256, 0, stream>>>(node, wallf, ball, qb, kb, vb, xr,
                                       es, wcef, bce, pos, eb);

  k_attn<<<(NN + 3)/4, 256, 0, stream>>>(off, cnt, srcs, qb, kb, vb, eb,
                                         xr, node, Wbeta, ln_g, ln_b, (float*)d_out);
}